// Round 1
// 626.082 us; speedup vs baseline: 1.0943x; 1.0943x over previous
//
#include <hip/hip_runtime.h>
#include <math.h>

#define DIM 16        // 2^Q, Q=4
#define BATCH 2       // B from setup_inputs
#define TT 16         // tokens per block in projection kernel

// ---------------------------------------------------------------------------
// Kernel A: embedding gather + normalize + noisy circuit + mask select.
// One thread per token (B*S = 4096 threads). 64-thread blocks -> 64 CUs busy.
// ---------------------------------------------------------------------------
__global__ void quantum_state_kernel(const int* __restrict__ ids,
                                     const int* __restrict__ mask,
                                     const float* __restrict__ W_embed,
                                     const float* __restrict__ gates,
                                     float* __restrict__ proc,
                                     int B, int S, int depth) {
    extern __shared__ float g[];                 // depth*DIM*DIM gate coeffs
    const int tid = threadIdx.x;
    const int ng = depth * DIM * DIM;
    for (int i = tid; i < ng; i += blockDim.x) g[i] = gates[i];
    __syncthreads();

    const int t = blockIdx.x * blockDim.x + tid; // token index b*S + s
    const int total = B * S;
    if (t >= total) return;
    const int s_idx = t % S;

    // embedding lookup + normalize: emb = row / (||row|| + 1e-12)
    const int id = ids[t];
    const float* row = W_embed + (long)id * DIM;
    float e[DIM];
    float ss = 0.f;
#pragma unroll
    for (int k = 0; k < DIM; ++k) { e[k] = row[k]; ss += e[k] * e[k]; }
    float inv = 1.0f / (sqrtf(ss) + 1e-12f);
#pragma unroll
    for (int k = 0; k < DIM; ++k) e[k] *= inv;

    // noisy circuit
    float st[DIM];
#pragma unroll
    for (int k = 0; k < DIM; ++k) st[k] = e[k];
    for (int l = 0; l < depth; ++l) {
        const float* gl = g + l * DIM * DIM;
        float ns[DIM];
#pragma unroll
        for (int ei = 0; ei < DIM; ++ei) {
            float acc = 0.f;
#pragma unroll
            for (int d = 0; d < DIM; ++d) acc += gl[ei * DIM + d] * st[d];
            ns[ei] = acc;
        }
        ss = 0.f;
#pragma unroll
        for (int k = 0; k < DIM; ++k) {
            float v = ns[k] * 0.99f;              // decoherence (1-0.01)
            v = 0.99f * v + 0.000625f;            // depolarization 0.99*x + 0.01/16
            ns[k] = v;
            ss += v * v;
        }
        inv = 1.0f / (sqrtf(ss) + 1e-12f);
#pragma unroll
        for (int k = 0; k < DIM; ++k) st[k] = ns[k] * inv;
    }
#pragma unroll
    for (int k = 0; k < DIM; ++k) st[k] = 0.99f * st[k] + 0.000625f;  // measurement error

    // apply only if mask[:, s] all nonzero
    bool apply = true;
    for (int b = 0; b < B; ++b) apply = apply && (mask[b * S + s_idx] != 0);

#pragma unroll
    for (int k = 0; k < DIM; ++k) proc[(long)t * DIM + k] = apply ? st[k] : e[k];
}

// ---------------------------------------------------------------------------
// Kernel B: out[t, v] = dot(proc[t,:], W_out[v,:]) + b_out[v]
// Block = 256 threads handles TT=16 tokens x 1024 vocab entries.
// Each thread owns 4 consecutive vocab rows. CRITICAL: every loop touching
// the w[4][16]/bias register tile has a COMPILE-TIME trip count so SROA keeps
// the tile in VGPRs (a runtime `nv` bound previously forced it to scratch,
// ~9 GB of local-memory traffic). After the early return and with V % 4 == 0,
// all 4 rows are provably in-bounds, so the static bound is exact.
// ---------------------------------------------------------------------------
__global__ __launch_bounds__(256) void out_proj_kernel(
        const float* __restrict__ proc,
        const float* __restrict__ W_out,
        const float* __restrict__ b_out,
        float* __restrict__ out,
        int V, int total_tokens) {
    __shared__ float sstate[TT][DIM];
    const int tid = threadIdx.x;
    const int t0 = blockIdx.x * TT;

    // 256 threads load exactly TT*DIM = 256 floats
    {
        const int tok = tid >> 4;
        const int k   = tid & 15;
        const int t   = t0 + tok;
        sstate[tok][k] = (t < total_tokens) ? proc[(long)t * DIM + k] : 0.f;
    }
    __syncthreads();

    const int v0 = blockIdx.y * 1024 + tid * 4;
    if (v0 >= V) return;           // V % 4 == 0  =>  v0..v0+3 all valid below

    // statically-indexed register tile: 4 W_out rows (64 VGPRs) + bias
    float w[4][DIM];
#pragma unroll
    for (int j = 0; j < 4; ++j) {
        const float4* wr = (const float4*)(W_out + (long)(v0 + j) * DIM);
        const float4 a = wr[0], b4 = wr[1], c = wr[2], d = wr[3];
        w[j][0]  = a.x;  w[j][1]  = a.y;  w[j][2]  = a.z;  w[j][3]  = a.w;
        w[j][4]  = b4.x; w[j][5]  = b4.y; w[j][6]  = b4.z; w[j][7]  = b4.w;
        w[j][8]  = c.x;  w[j][9]  = c.y;  w[j][10] = c.z;  w[j][11] = c.w;
        w[j][12] = d.x;  w[j][13] = d.y;  w[j][14] = d.z;  w[j][15] = d.w;
    }
    const float4 bias = *(const float4*)(b_out + v0);   // v0 % 4 == 0 -> 16B aligned

#pragma unroll
    for (int tk = 0; tk < TT; ++tk) {
        const int t = t0 + tk;
        if (t < total_tokens) {
            // wave-uniform LDS address -> ds_read_b128 broadcast, 4 reads/token
            const float4* sp = (const float4*)sstate[tk];
            const float4 s0 = sp[0], s1 = sp[1], s2 = sp[2], s3 = sp[3];
            const float sv[DIM] = {s0.x, s0.y, s0.z, s0.w,
                                   s1.x, s1.y, s1.z, s1.w,
                                   s2.x, s2.y, s2.z, s2.w,
                                   s3.x, s3.y, s3.z, s3.w};
            float a0 = bias.x, a1 = bias.y, a2 = bias.z, a3 = bias.w;
#pragma unroll
            for (int k = 0; k < DIM; ++k) {
                a0 = fmaf(sv[k], w[0][k], a0);
                a1 = fmaf(sv[k], w[1][k], a1);
                a2 = fmaf(sv[k], w[2][k], a2);
                a3 = fmaf(sv[k], w[3][k], a3);
            }
            *(float4*)(out + (long)t * V + v0) = make_float4(a0, a1, a2, a3);
        }
    }
}

extern "C" void kernel_launch(void* const* d_in, const int* in_sizes, int n_in,
                              void* d_out, int out_size, void* d_ws, size_t ws_size,
                              hipStream_t stream) {
    const int*   ids    = (const int*)  d_in[0];  // [B,S]
    const int*   mask   = (const int*)  d_in[1];  // [B,S]
    const float* W_emb  = (const float*)d_in[2];  // [V,16]
    const float* gates  = (const float*)d_in[3];  // [depth,16,16]
    const float* W_out  = (const float*)d_in[4];  // [V,16]
    const float* b_out  = (const float*)d_in[5];  // [V]
    float* out = (float*)d_out;

    const int B = BATCH;
    const int total = in_sizes[0];          // B*S
    const int S = total / B;
    const int V = in_sizes[5];
    const int depth = in_sizes[3] / (DIM * DIM);

    float* proc = (float*)d_ws;             // [total, DIM] scratch (256 KB)

    // Kernel A: tiny — compute processed states (64-thread blocks -> 64 CUs)
    {
        dim3 block(64);
        dim3 grid((total + 63) / 64);
        size_t shmem = (size_t)depth * DIM * DIM * sizeof(float);
        quantum_state_kernel<<<grid, block, shmem, stream>>>(
            ids, mask, W_emb, gates, proc, B, S, depth);
    }

    // Kernel B: projection, write-bound
    {
        dim3 block(256);
        dim3 grid((total + TT - 1) / TT, (V + 1023) / 1024);
        out_proj_kernel<<<grid, block, 0, stream>>>(proc, W_out, b_out, out, V, total);
    }
}

// Round 2
// 548.160 us; speedup vs baseline: 1.2498x; 1.1422x over previous
//
#include <hip/hip_runtime.h>
#include <math.h>

#define DIM 16        // 2^Q, Q=4
#define BATCH 2       // B from setup_inputs
#define TT 32         // tokens per block in projection kernel

typedef float f32x4  __attribute__((ext_vector_type(4)));
typedef float f32x16 __attribute__((ext_vector_type(16)));

// ---------------------------------------------------------------------------
// Kernel A: embedding gather + normalize + noisy circuit + mask select.
// One thread per token (B*S = 4096 threads). 64-thread blocks -> 64 CUs busy.
// All 16-float rows are 64-B aligned (row index * 64 B), so f32x16 loads are
// legal and emit 4x dwordx4.
// ---------------------------------------------------------------------------
__global__ void quantum_state_kernel(const int* __restrict__ ids,
                                     const int* __restrict__ mask,
                                     const float* __restrict__ W_embed,
                                     const float* __restrict__ gates,
                                     float* __restrict__ proc,
                                     int B, int S, int depth) {
    extern __shared__ float g[];                 // depth*DIM*DIM gate coeffs
    const int tid = threadIdx.x;
    const int ng = depth * DIM * DIM;
    for (int i = tid; i < ng; i += blockDim.x) g[i] = gates[i];
    __syncthreads();

    const int t = blockIdx.x * blockDim.x + tid; // token index b*S + s
    const int total = B * S;
    if (t >= total) return;
    const int s_idx = t % S;

    // embedding lookup + normalize: emb = row / (||row|| + 1e-12)
    const int id = ids[t];
    f32x16 e = *(const f32x16*)(W_embed + (size_t)id * DIM);
    float ss = 0.f;
#pragma unroll
    for (int k = 0; k < DIM; ++k) ss += e[k] * e[k];
    float inv = 1.0f / (sqrtf(ss) + 1e-12f);
#pragma unroll
    for (int k = 0; k < DIM; ++k) e[k] *= inv;

    // noisy circuit
    f32x16 st = e;
    for (int l = 0; l < depth; ++l) {
        const float* gl = g + l * DIM * DIM;
        f32x16 ns;
#pragma unroll
        for (int ei = 0; ei < DIM; ++ei) {
            float acc = 0.f;
#pragma unroll
            for (int d = 0; d < DIM; ++d) acc += gl[ei * DIM + d] * st[d];
            ns[ei] = acc;
        }
        ss = 0.f;
#pragma unroll
        for (int k = 0; k < DIM; ++k) {
            float v = ns[k] * 0.99f;              // decoherence (1-0.01)
            v = 0.99f * v + 0.000625f;            // depolarization 0.99*x + 0.01/16
            ns[k] = v;
            ss += v * v;
        }
        inv = 1.0f / (sqrtf(ss) + 1e-12f);
#pragma unroll
        for (int k = 0; k < DIM; ++k) st[k] = ns[k] * inv;
    }
#pragma unroll
    for (int k = 0; k < DIM; ++k) st[k] = 0.99f * st[k] + 0.000625f;  // measurement error

    // apply only if mask[:, s] all nonzero
    bool apply = true;
    for (int b = 0; b < B; ++b) apply = apply && (mask[b * S + s_idx] != 0);

    *(f32x16*)(proc + (size_t)t * DIM) = apply ? st : e;   // 4x dwordx4 store
}

// ---------------------------------------------------------------------------
// Kernel B: out[t, v] = dot(proc[t,:], W_out[v,:]) + b_out[v]
// Block = 256 threads handles TT=32 tokens x 1024 vocab entries.
// - W_out tile lives in ext_vector registers (constant-indexed => SSA, can
//   never demote to scratch). TT=32 doubles reuse of the strided W_out load
//   (each dwordx4 touches 64 cache lines/wave -- the expensive part).
// - Token state is loaded at a WAVE-UNIFORM address (depends only on
//   blockIdx.x and the loop counter) => compiler can emit s_load_dwordx16
//   into SGPRs; no LDS, no __syncthreads.
// - Output uses nontemporal stores: 524 MB streams past L2 without evicting
//   the cached W_out working set.
// ---------------------------------------------------------------------------
__global__ __launch_bounds__(256) void out_proj_kernel(
        const float* __restrict__ proc,
        const float* __restrict__ W_out,
        const float* __restrict__ b_out,
        float* __restrict__ out,
        int V, int total_tokens) {
    const int tid = threadIdx.x;
    const int t0 = blockIdx.x * TT;
    const int v0 = blockIdx.y * 1024 + tid * 4;
    if (v0 >= V) return;           // V % 4 == 0 => v0..v0+3 all valid below

    // 4 vocab rows, 64 VGPRs, statically indexed only
    const f32x16 w0 = *(const f32x16*)(W_out + (size_t)(v0 + 0) * DIM);
    const f32x16 w1 = *(const f32x16*)(W_out + (size_t)(v0 + 1) * DIM);
    const f32x16 w2 = *(const f32x16*)(W_out + (size_t)(v0 + 2) * DIM);
    const f32x16 w3 = *(const f32x16*)(W_out + (size_t)(v0 + 3) * DIM);
    const f32x4 bias = *(const f32x4*)(b_out + v0);   // v0 % 4 == 0 -> 16B aligned

#pragma unroll 2
    for (int tk = 0; tk < TT; ++tk) {
        const int t = t0 + tk;
        if (t >= total_tokens) break;
        // wave-uniform address -> scalar (SMEM) load of the whole 64-B state
        const f32x16 sv = *(const f32x16*)(proc + (size_t)t * DIM);
        float a0 = bias[0], a1 = bias[1], a2 = bias[2], a3 = bias[3];
#pragma unroll
        for (int k = 0; k < DIM; ++k) {
            a0 = fmaf(sv[k], w0[k], a0);
            a1 = fmaf(sv[k], w1[k], a1);
            a2 = fmaf(sv[k], w2[k], a2);
            a3 = fmaf(sv[k], w3[k], a3);
        }
        f32x4 r; r[0] = a0; r[1] = a1; r[2] = a2; r[3] = a3;
        __builtin_nontemporal_store(r, (f32x4*)(out + (size_t)t * V + v0));
    }
}

extern "C" void kernel_launch(void* const* d_in, const int* in_sizes, int n_in,
                              void* d_out, int out_size, void* d_ws, size_t ws_size,
                              hipStream_t stream) {
    const int*   ids    = (const int*)  d_in[0];  // [B,S]
    const int*   mask   = (const int*)  d_in[1];  // [B,S]
    const float* W_emb  = (const float*)d_in[2];  // [V,16]
    const float* gates  = (const float*)d_in[3];  // [depth,16,16]
    const float* W_out  = (const float*)d_in[4];  // [V,16]
    const float* b_out  = (const float*)d_in[5];  // [V]
    float* out = (float*)d_out;

    const int B = BATCH;
    const int total = in_sizes[0];          // B*S
    const int S = total / B;
    const int V = in_sizes[5];
    const int depth = in_sizes[3] / (DIM * DIM);

    float* proc = (float*)d_ws;             // [total, DIM] scratch (256 KB)

    // Kernel A: tiny — compute processed states (64-thread blocks -> 64 CUs)
    {
        dim3 block(64);
        dim3 grid((total + 63) / 64);
        size_t shmem = (size_t)depth * DIM * DIM * sizeof(float);
        quantum_state_kernel<<<grid, block, shmem, stream>>>(
            ids, mask, W_emb, gates, proc, B, S, depth);
    }

    // Kernel B: projection, write-bound
    {
        dim3 block(256);
        dim3 grid((total + TT - 1) / TT, (V + 1023) / 1024);
        out_proj_kernel<<<grid, block, 0, stream>>>(proc, W_out, b_out, out, V, total);
    }
}